// Round 10
// baseline (661.393 us; speedup 1.0000x reference)
//
#include <hip/hip_runtime.h>
#include <cstdint>

#define NB 32
#define NN 1000
#define NC 1601
#define HID 64
#define ROWS (NB*NN)       // 32000
#define CAPB 15360         // candidate cap per batch
#define SROWS 15           // sample rows for threshold floor
#define NBIN 4096          // 12-bit key-prefix histogram
#define KCH 32             // mlp k-chunk
#define RB 64              // mlp rows per block
#define TPB 256            // mlp threads per block
#define XSTR 68            // 64 rows + 4 pad (16B-aligned b128 reads)
#define WSTR 132           // W chunk row stride: 128 cols + 4 pad
#define SSTR 132           // score tile row stride: 128 + 4 pad

__device__ __forceinline__ uint32_t f2key(float f){
  uint32_t u = __float_as_uint(f);
  return (u & 0x80000000u) ? ~u : (u | 0x80000000u);   // monotone float->uint
}
__device__ __forceinline__ float key2f(uint32_t k){
  uint32_t u = (k & 0x80000000u) ? (k & 0x7fffffffu) : ~k;
  return __uint_as_float(u);
}

// ---------------------------------------------------------------------------
// Kernel A: fused 2-layer MLP, tiled GEMM.
// R10: R9 structure (256 thr, 4x(4S+4O) tile, W1-in-LDS dbuf; 254us,
// VALUBusy 46.5%, VGPR 68 -> LDS-delivery-bound per counter arithmetic)
// + depth-2 software pipeline of inner-loop LDS reads: fragments for
// k+2/k+3 are issued BEFORE the FMAs of k/k+1 (~128 FMA-cyc of cover
// vs ~120cyc LDS latency; compiler at VGPR=68 was not prefetching).
// FMA order per output element unchanged (k ascending, single chain)
// -> bit-identical results. +~24 VGPR, occupancy unchanged.
// ---------------------------------------------------------------------------
__global__ __launch_bounds__(TPB, 2) void mlp_kernel(
    const float* __restrict__ x,
    const float* __restrict__ Ws1, const float* __restrict__ bs1,
    const float* __restrict__ Ws2, const float* __restrict__ bs2,
    const float* __restrict__ Wo1, const float* __restrict__ bo1,
    const float* __restrict__ Wo2, const float* __restrict__ bo2,
    float* __restrict__ subj, float* __restrict__ obj)
{
  __shared__ float smem[2*KCH*XSTR + 2*KCH*WSTR];  // 51200 B; reused as hT
  __shared__ float xtail[RB];
  const int tid = threadIdx.x;
  const int tx  = tid & 15;            // col group: subj tx*4..+3, obj tx*4..+3
  const int ty  = tid >> 4;            // row group: rows ty*4..+3 (0..15)
  const int row0 = blockIdx.x * RB;

  float* xbuf = smem;                  // 2 * 32*68
  float* wbuf = smem + 2*KCH*XSTR;     // 2 * 32*132

  float accS[4][4], accO[4][4];
  #pragma unroll
  for (int r=0;r<4;r++)
    #pragma unroll
    for (int c=0;c<4;c++){ accS[r][c]=0.f; accO[r][c]=0.f; }

  // prologue: chunk 0 into regs (x: 2048 floats, W: 1024 float4)
  float  xstg[8];
  float4 wstg[4];
  #pragma unroll
  for (int it=0; it<8; it++){
    int u = tid + it*TPB;
    xstg[it] = x[(size_t)(row0 + (u>>5))*NC + (u&31)];
  }
  #pragma unroll
  for (int it=0; it<4; it++){
    int u = tid + it*TPB;
    int k = u>>5, c4 = u&31;
    const float* src = (c4 < 16) ? (Ws1 + (size_t)k*HID + c4*4)
                                 : (Wo1 + (size_t)k*HID + (c4-16)*4);
    wstg[it] = *(const float4*)src;
  }

  const int NCHUNK = 50;               // 50*32 = 1600, tail k=1600 after
  for (int c = 0; c < NCHUNK; c++){
    float* xT = xbuf + (c & 1)*(KCH*XSTR);
    float* wC = wbuf + (c & 1)*(KCH*WSTR);
    #pragma unroll
    for (int it=0; it<8; it++){
      int u = tid + it*TPB;
      xT[(u&31)*XSTR + (u>>5)] = xstg[it];
    }
    #pragma unroll
    for (int it=0; it<4; it++){
      int u = tid + it*TPB;
      *(float4*)&wC[(u>>5)*WSTR + (u&31)*4] = wstg[it];
    }
    __syncthreads();                   // buffer c ready; buffer c^1 free
    if (c+1 < NCHUNK){
      const int k0n = (c+1)*KCH;
      #pragma unroll
      for (int it=0; it<8; it++){      // global latency hidden by compute(c)
        int u = tid + it*TPB;
        xstg[it] = x[(size_t)(row0 + (u>>5))*NC + k0n + (u&31)];
      }
      #pragma unroll
      for (int it=0; it<4; it++){
        int u = tid + it*TPB;
        int k = u>>5, c4 = u&31;
        const float* src = (c4 < 16) ? (Ws1 + (size_t)(k0n+k)*HID + c4*4)
                                     : (Wo1 + (size_t)(k0n+k)*HID + (c4-16)*4);
        wstg[it] = *(const float4*)src;
      }
    }
    // ---- depth-2 pipelined inner loop: load k+2/k+3 before FMA(k,k+1) ----
    float4 aC = *(const float4*)&xT[0*XSTR + ty*4];
    float4 sC = *(const float4*)&wC[0*WSTR + tx*4];
    float4 oC = *(const float4*)&wC[0*WSTR + 64 + tx*4];
    float4 aN = *(const float4*)&xT[1*XSTR + ty*4];
    float4 sN = *(const float4*)&wC[1*WSTR + tx*4];
    float4 oN = *(const float4*)&wC[1*WSTR + 64 + tx*4];
    #pragma unroll
    for (int k = 0; k < KCH; k += 2){
      float4 a2 = aC, s2 = sC, o2 = oC, a3 = aN, s3 = sN, o3 = oN;
      if (k + 2 < KCH){
        a2 = *(const float4*)&xT[(k+2)*XSTR + ty*4];
        s2 = *(const float4*)&wC[(k+2)*WSTR + tx*4];
        o2 = *(const float4*)&wC[(k+2)*WSTR + 64 + tx*4];
        a3 = *(const float4*)&xT[(k+3)*XSTR + ty*4];
        s3 = *(const float4*)&wC[(k+3)*WSTR + tx*4];
        o3 = *(const float4*)&wC[(k+3)*WSTR + 64 + tx*4];
      }
      {
        float av[4] = {aC.x,aC.y,aC.z,aC.w};
        float bs_[4] = {sC.x,sC.y,sC.z,sC.w};
        float bo_[4] = {oC.x,oC.y,oC.z,oC.w};
        #pragma unroll
        for (int r=0;r<4;r++)
          #pragma unroll
          for (int c2=0;c2<4;c2++){
            accS[r][c2] = fmaf(av[r], bs_[c2], accS[r][c2]);
            accO[r][c2] = fmaf(av[r], bo_[c2], accO[r][c2]);
          }
      }
      {
        float av[4] = {aN.x,aN.y,aN.z,aN.w};
        float bs_[4] = {sN.x,sN.y,sN.z,sN.w};
        float bo_[4] = {oN.x,oN.y,oN.z,oN.w};
        #pragma unroll
        for (int r=0;r<4;r++)
          #pragma unroll
          for (int c2=0;c2<4;c2++){
            accS[r][c2] = fmaf(av[r], bs_[c2], accS[r][c2]);
            accO[r][c2] = fmaf(av[r], bo_[c2], accO[r][c2]);
          }
      }
      aC = a2; sC = s2; oC = o2;
      aN = a3; sN = s3; oN = o3;
    }
  }

  // tail k = 1600 (W via global: 2 loads total, negligible)
  if (tid < RB) xtail[tid] = x[(size_t)(row0 + tid)*NC + 1600];
  __syncthreads();
  {
    float4 a  = *(const float4*)&xtail[ty*4];
    float4 bS = *(const float4*)(Ws1 + (size_t)1600*HID + tx*4);
    float4 bO = *(const float4*)(Wo1 + (size_t)1600*HID + tx*4);
    float av[4] = {a.x,a.y,a.z,a.w};
    float bs_[4] = {bS.x,bS.y,bS.z,bS.w};
    float bo_[4] = {bO.x,bO.y,bO.z,bO.w};
    #pragma unroll
    for (int r=0;r<4;r++)
      #pragma unroll
      for (int c2=0;c2<4;c2++){
        accS[r][c2] = fmaf(av[r], bs_[c2], accS[r][c2]);
        accO[r][c2] = fmaf(av[r], bo_[c2], accO[r][c2]);
      }
  }

  // ---- layer 2: h (bias+ReLU) -> LDS transposed, both heads at once ----
  float* hTS = smem;                   // 64*68
  float* hTO = smem + 64*XSTR;         // 64*68  (34816B total, fits 51456)
  __syncthreads();                     // all xT/wC reads done
  #pragma unroll
  for (int jj=0; jj<4; jj++){
    float bS = bs1[tx*4 + jj];
    float bO = bo1[tx*4 + jj];
    float4 hv;
    hv.x = fmaxf(accS[0][jj]+bS, 0.f); hv.y = fmaxf(accS[1][jj]+bS, 0.f);
    hv.z = fmaxf(accS[2][jj]+bS, 0.f); hv.w = fmaxf(accS[3][jj]+bS, 0.f);
    *(float4*)&hTS[(tx*4+jj)*XSTR + ty*4] = hv;
    hv.x = fmaxf(accO[0][jj]+bO, 0.f); hv.y = fmaxf(accO[1][jj]+bO, 0.f);
    hv.z = fmaxf(accO[2][jj]+bO, 0.f); hv.w = fmaxf(accO[3][jj]+bO, 0.f);
    *(float4*)&hTO[(tx*4+jj)*XSTR + ty*4] = hv;
  }
  __syncthreads();

  float accYS[4][4], accYO[4][4];
  #pragma unroll
  for (int c2=0;c2<4;c2++){
    float bvS = bs2[tx*4 + c2];
    float bvO = bo2[tx*4 + c2];
    #pragma unroll
    for (int r=0;r<4;r++){ accYS[r][c2] = bvS; accYO[r][c2] = bvO; }
  }
  #pragma unroll 4
  for (int d=0; d<64; d++){
    float4 aS = *(const float4*)&hTS[d*XSTR + ty*4];
    float4 aO = *(const float4*)&hTO[d*XSTR + ty*4];
    float4 wS = *(const float4*)(Ws2 + (size_t)d*HID + tx*4);
    float4 wO = *(const float4*)(Wo2 + (size_t)d*HID + tx*4);
    float aSv[4] = {aS.x,aS.y,aS.z,aS.w};
    float aOv[4] = {aO.x,aO.y,aO.z,aO.w};
    float wSv[4] = {wS.x,wS.y,wS.z,wS.w};
    float wOv[4] = {wO.x,wO.y,wO.z,wO.w};
    #pragma unroll
    for (int r=0;r<4;r++)
      #pragma unroll
      for (int c2=0;c2<4;c2++){
        accYS[r][c2] = fmaf(aSv[r], wSv[c2], accYS[r][c2]);
        accYO[r][c2] = fmaf(aOv[r], wOv[c2], accYO[r][c2]);
      }
  }
  #pragma unroll
  for (int r=0;r<4;r++){
    *(float4*)&subj[(size_t)(row0 + ty*4 + r)*HID + tx*4] =
      make_float4(accYS[r][0], accYS[r][1], accYS[r][2], accYS[r][3]);
    *(float4*)&obj[(size_t)(row0 + ty*4 + r)*HID + tx*4] =
      make_float4(accYO[r][0], accYO[r][1], accYO[r][2], accYO[r][3]);
  }
}

// ---------------------------------------------------------------------------
// Kernel B0: per-batch sampled FLOOR. Subset 64th <= full 64th.
// ---------------------------------------------------------------------------
__global__ __launch_bounds__(1024, 4) void sample_thresh(
    const float* __restrict__ subj, const float* __restrict__ obj,
    uint32_t* __restrict__ L)
{
  __shared__ float sRows[SROWS*HID];
  __shared__ uint32_t keys[SROWS*NN];
  __shared__ uint32_t hist[256];
  __shared__ uint32_t sb[2];
  const int b = blockIdx.x, tid = threadIdx.x;

  const float4* sp = (const float4*)(subj + (size_t)b*NN*HID);
  if (tid < SROWS*16) ((float4*)sRows)[tid] = sp[tid];
  __syncthreads();

  for (int j = tid; j < NN; j += 1024){
    const float4* op4 = (const float4*)(obj + ((size_t)b*NN + j)*HID);
    float4 o[16];
    #pragma unroll
    for (int q=0;q<16;q++) o[q] = op4[q];
    #pragma unroll 1
    for (int i=0;i<SROWS;i++){
      const float4* s4 = (const float4*)(sRows + i*HID);
      float acc = 0.f;
      #pragma unroll
      for (int q=0;q<16;q++){
        float4 s = s4[q];
        acc = fmaf(s.x, o[q].x, acc); acc = fmaf(s.y, o[q].y, acc);
        acc = fmaf(s.z, o[q].z, acc); acc = fmaf(s.w, o[q].w, acc);
      }
      keys[i*NN + j] = f2key(acc);
    }
  }
  __syncthreads();

  uint32_t prefix = 0; int remaining = 64;
  for (int round = 0; round < 2; round++){
    const int shift = 24 - round*8;
    if (tid < 256) hist[tid] = 0;
    __syncthreads();
    for (int idx = tid; idx < SROWS*NN; idx += 1024){
      uint32_t k = keys[idx];
      bool match = (round == 0) || ((k >> 24) == (prefix >> 24));
      if (match) atomicAdd(&hist[(k >> shift) & 255u], 1u);
    }
    __syncthreads();
    if (tid == 0){
      uint32_t cum = 0; int bin = 255;
      for (;; bin--){ cum += hist[bin]; if (cum >= (uint32_t)remaining || bin == 0) break; }
      sb[0] = (uint32_t)bin;
      sb[1] = (uint32_t)(remaining - (int)(cum - hist[bin]));
    }
    __syncthreads();
    prefix |= sb[0] << shift;
    remaining = (int)sb[1];
    __syncthreads();
  }
  if (tid == 0) L[b] = prefix;
}

// ---------------------------------------------------------------------------
// Shared tile-compute for B1/B3: 128x128 tile, k staged in 2 chunks of 32,
// both tiles k-major stride 132 -> b128 fragment reads (broadcast / 4-way).
// FMA chains k-ascending: bitwise-identical across B1 and B3.
// ---------------------------------------------------------------------------
__device__ __forceinline__ void score_tile_acc(
    const float* __restrict__ subj, const float* __restrict__ obj,
    int b, int ti, int tj, int tid,
    float* __restrict__ sT, float* __restrict__ oT, float (&acc)[8][8])
{
  const int tx = tid & 15, ty = tid >> 4;
  #pragma unroll
  for (int a=0;a<8;a++)
    #pragma unroll
    for (int c=0;c<8;c++) acc[a][c] = 0.f;

  #pragma unroll 1
  for (int half = 0; half < 2; half++){
    __syncthreads();                   // previous chunk's reads done
    {
      const float4* gp = (const float4*)subj;
      #pragma unroll
      for (int it=0; it<4; it++){
        int u = tid + it*256;
        int r = u >> 3, q = (u & 7) + half*8;
        int gr = b*NN + ti + r; gr = gr < ROWS ? gr : (ROWS-1);
        float4 v = gp[(size_t)gr*16 + q];
        int kk = (u & 7)*4;
        sT[(kk+0)*SSTR + r] = v.x;
        sT[(kk+1)*SSTR + r] = v.y;
        sT[(kk+2)*SSTR + r] = v.z;
        sT[(kk+3)*SSTR + r] = v.w;
      }
      const float4* gp2 = (const float4*)obj;
      #pragma unroll
      for (int it=0; it<4; it++){
        int u = tid + it*256;
        int r = u >> 3, q = (u & 7) + half*8;
        int gr = b*NN + tj + r; gr = gr < ROWS ? gr : (ROWS-1);
        float4 v = gp2[(size_t)gr*16 + q];
        int kk = (u & 7)*4;
        oT[(kk+0)*SSTR + r] = v.x;
        oT[(kk+1)*SSTR + r] = v.y;
        oT[(kk+2)*SSTR + r] = v.z;
        oT[(kk+3)*SSTR + r] = v.w;
      }
    }
    __syncthreads();
    #pragma unroll 2
    for (int k=0; k<32; k++){
      float4 s0 = *(const float4*)&sT[k*SSTR + ty*8];
      float4 s1 = *(const float4*)&sT[k*SSTR + ty*8 + 4];
      float4 o0 = *(const float4*)&oT[k*SSTR + tx*8];
      float4 o1 = *(const float4*)&oT[k*SSTR + tx*8 + 4];
      float s[8] = {s0.x,s0.y,s0.z,s0.w,s1.x,s1.y,s1.z,s1.w};
      float o[8] = {o0.x,o0.y,o0.z,o0.w,o1.x,o1.y,o1.z,o1.w};
      #pragma unroll
      for (int a=0;a<8;a++)
        #pragma unroll
        for (int c=0;c<8;c++)
          acc[a][c] = fmaf(s[a], o[c], acc[a][c]);
    }
  }
}

// ---------------------------------------------------------------------------
// Kernel B1: score tiles; 12-bit histogram of keys >= L[b] + candidate
// append via two-phase reservation (1 global atomic per block).
// ---------------------------------------------------------------------------
__global__ __launch_bounds__(256, 3) void score_pass1(
    const float* __restrict__ subj, const float* __restrict__ obj,
    const uint32_t* __restrict__ L, uint32_t* __restrict__ cnt,
    uint2* __restrict__ cand, uint32_t* __restrict__ ghist)
{
  __shared__ float sT[32*SSTR];       // 16896 B
  __shared__ float oT[32*SSTR];       // 16896 B
  __shared__ uint32_t hist[NBIN];     // 16384 B
  __shared__ uint32_t lcnt, gbase;
  const int blk = blockIdx.x;
  const int b   = blk >> 6;
  const int t   = blk & 63;
  const int ti  = (t >> 3) << 7;
  const int tj  = (t & 7)  << 7;
  const int tid = threadIdx.x;
  const int tx = tid & 15, ty = tid >> 4;

  for (int i = tid; i < NBIN; i += 256) hist[i] = 0;
  if (tid == 0) lcnt = 0;

  float acc[8][8];
  score_tile_acc(subj, obj, b, ti, tj, tid, sT, oT, acc);

  const uint32_t Lb = L[b];
  int myCnt = 0;
  #pragma unroll
  for (int a=0;a<8;a++){
    int gi = ti + ty*8 + a;
    #pragma unroll
    for (int c=0;c<8;c++){
      int gj = tj + tx*8 + c;
      if (gi < NN && gj < NN){
        uint32_t key = f2key(acc[a][c]);
        if (key >= Lb){ myCnt++; atomicAdd(&hist[key >> 20], 1u); }
      }
    }
  }
  uint32_t lbase = atomicAdd(&lcnt, (uint32_t)myCnt);
  __syncthreads();
  if (tid == 0) gbase = atomicAdd(&cnt[b], lcnt);
  __syncthreads();
  uint32_t pos = gbase + lbase;
  #pragma unroll
  for (int a=0;a<8;a++){
    int gi = ti + ty*8 + a;
    #pragma unroll
    for (int c=0;c<8;c++){
      int gj = tj + tx*8 + c;
      if (gi < NN && gj < NN){
        uint32_t key = f2key(acc[a][c]);
        if (key >= Lb){
          if (pos < CAPB) cand[(size_t)b*CAPB + pos] = make_uint2(key, (uint32_t)(gi*NN + gj));
          pos++;
        }
      }
    }
  }
  __syncthreads();
  for (int i = tid; i < NBIN; i += 256){
    uint32_t v = hist[i];
    if (v) atomicAdd(&ghist[(size_t)b*NBIN + i], v);
  }
}

// ---------------------------------------------------------------------------
// Kernel B2: exact 12-bit bucket floor T[b] of the 64th-largest key;
// flag[b] = candidate overflow.
// ---------------------------------------------------------------------------
__global__ __launch_bounds__(256, 1) void pick_thresh(
    const uint32_t* __restrict__ ghist, const uint32_t* __restrict__ cnt,
    uint32_t* __restrict__ T, uint32_t* __restrict__ flag)
{
  __shared__ uint32_t S[256];
  const int b = blockIdx.x, tid = threadIdx.x;
  const uint32_t* h = ghist + (size_t)b*NBIN;
  uint32_t loc[16];
  uint32_t s = 0;
  #pragma unroll
  for (int i=0;i<16;i++){ loc[i] = h[tid*16 + i]; s += loc[i]; }
  S[tid] = s;
  __syncthreads();
  for (int off = 1; off < 256; off <<= 1){
    uint32_t v = (tid + off < 256) ? S[tid + off] : 0u;
    __syncthreads();
    S[tid] += v;
    __syncthreads();
  }
  uint32_t above = (tid < 255) ? S[tid + 1] : 0u;
  if (above < 64u && S[tid] >= 64u){
    uint32_t suf = above; int best = 0;
    for (int i=15;i>=0;i--){ suf += loc[i]; if (suf >= 64u){ best = i; break; } }
    T[b] = (uint32_t)(tid*16 + best) << 20;
  }
  if (tid == 0) flag[b] = (cnt[b] > (uint32_t)CAPB) ? 1u : 0u;
}

// ---------------------------------------------------------------------------
// Kernel B3: repair pass for overflowed batches (early-exit common case).
// Identical dot chains to B1.
// ---------------------------------------------------------------------------
__global__ __launch_bounds__(256, 3) void score_repair(
    const float* __restrict__ subj, const float* __restrict__ obj,
    const uint32_t* __restrict__ T, const uint32_t* __restrict__ flag,
    uint32_t* __restrict__ cnt2, uint2* __restrict__ cand)
{
  const int blk = blockIdx.x;
  const int b   = blk >> 6;
  if (flag[b] == 0u) return;

  __shared__ float sT[32*SSTR];
  __shared__ float oT[32*SSTR];
  __shared__ uint32_t lcnt, gbase;
  const int t   = blk & 63;
  const int ti  = (t >> 3) << 7;
  const int tj  = (t & 7)  << 7;
  const int tid = threadIdx.x;
  const int tx = tid & 15, ty = tid >> 4;

  if (tid == 0) lcnt = 0;

  float acc[8][8];
  score_tile_acc(subj, obj, b, ti, tj, tid, sT, oT, acc);

  const uint32_t Tb = T[b];
  int myCnt = 0;
  #pragma unroll
  for (int a=0;a<8;a++){
    int gi = ti + ty*8 + a;
    #pragma unroll
    for (int c=0;c<8;c++){
      int gj = tj + tx*8 + c;
      if (gi < NN && gj < NN && f2key(acc[a][c]) >= Tb) myCnt++;
    }
  }
  uint32_t lbase = atomicAdd(&lcnt, (uint32_t)myCnt);
  __syncthreads();
  if (tid == 0) gbase = atomicAdd(&cnt2[b], lcnt);
  __syncthreads();
  uint32_t pos = gbase + lbase;
  #pragma unroll
  for (int a=0;a<8;a++){
    int gi = ti + ty*8 + a;
    #pragma unroll
    for (int c=0;c<8;c++){
      int gj = tj + tx*8 + c;
      if (gi < NN && gj < NN){
        uint32_t key = f2key(acc[a][c]);
        if (key >= Tb){
          if (pos < CAPB) cand[(size_t)b*CAPB + pos] = make_uint2(key, (uint32_t)(gi*NN + gj));
          pos++;
        }
      }
    }
  }
}

// ---------------------------------------------------------------------------
// Kernel C: exact top-64 per batch. Radix-select 64th key, rank by
// (value desc, index asc) = jax.lax.top_k tie semantics.
// ---------------------------------------------------------------------------
__global__ __launch_bounds__(1024, 4) void final_select(
    const uint32_t* __restrict__ cnt, const uint32_t* __restrict__ cnt2,
    const uint32_t* __restrict__ flag, const uint2* __restrict__ cand,
    float* __restrict__ out)
{
  __shared__ uint32_t keys[CAPB];
  __shared__ uint32_t hist[256];
  __shared__ uint32_t sb[2];
  __shared__ uint2 win[192];
  __shared__ uint32_t wn;
  const int b = blockIdx.x, tid = threadIdx.x;
  uint32_t n0 = flag[b] ? cnt2[b] : cnt[b];
  const int n = (n0 < (uint32_t)CAPB) ? (int)n0 : CAPB;

  for (int i = tid; i < n; i += 1024) keys[i] = cand[(size_t)b*CAPB + i].x;
  if (tid == 0) wn = 0;
  __syncthreads();

  uint32_t prefix = 0; int remaining = 64;
  for (int round = 0; round < 4; round++){
    const int shift = 24 - round*8;
    if (tid < 256) hist[tid] = 0;
    __syncthreads();
    for (int i = tid; i < n; i += 1024){
      uint32_t k = keys[i];
      bool match = (round == 0) || ((k >> (shift+8)) == (prefix >> (shift+8)));
      if (match) atomicAdd(&hist[(k >> shift) & 255u], 1u);
    }
    __syncthreads();
    if (tid == 0){
      uint32_t cum = 0; int bin = 255;
      for (;; bin--){ cum += hist[bin]; if (cum >= (uint32_t)remaining || bin == 0) break; }
      sb[0] = (uint32_t)bin;
      sb[1] = (uint32_t)(remaining - (int)(cum - hist[bin]));
    }
    __syncthreads();
    prefix |= sb[0] << shift;
    remaining = (int)sb[1];
    __syncthreads();
  }
  const uint32_t Tk = prefix;

  for (int i = tid; i < n; i += 1024){
    if (keys[i] >= Tk){
      uint32_t p = atomicAdd(&wn, 1u);
      if (p < 192u) win[p] = make_uint2(keys[i], cand[(size_t)b*CAPB + i].y);
    }
  }
  __syncthreads();
  const int m = (wn < 192u) ? (int)wn : 192;

  if (tid < m){
    const uint64_t me = ((uint64_t)win[tid].x << 32) | (uint64_t)(uint32_t)(~win[tid].y);
    int rank = 0;
    for (int s = 0; s < m; s++){
      uint64_t oth = ((uint64_t)win[s].x << 32) | (uint64_t)(uint32_t)(~win[s].y);
      rank += (oth > me) ? 1 : 0;
    }
    if (rank < 64){
      const uint32_t f = win[tid].y;
      const float d  = key2f(win[tid].x);
      const float sc = 1.0f / (1.0f + expf(-d));
      out[((size_t)b*64 + rank)*2 + 0] = (float)(f / NN);
      out[((size_t)b*64 + rank)*2 + 1] = (float)(f % NN);
      out[(size_t)NB*64*2 + (size_t)b*64 + rank] = sc;
    }
  }
}

// ---------------------------------------------------------------------------
extern "C" void kernel_launch(void* const* d_in, const int* in_sizes, int n_in,
                              void* d_out, int out_size, void* d_ws, size_t ws_size,
                              hipStream_t stream) {
  const float* x   = (const float*)d_in[0];
  const float* Ws1 = (const float*)d_in[2];
  const float* bs1 = (const float*)d_in[3];
  const float* Ws2 = (const float*)d_in[4];
  const float* bs2 = (const float*)d_in[5];
  const float* Wo1 = (const float*)d_in[6];
  const float* bo1 = (const float*)d_in[7];
  const float* Wo2 = (const float*)d_in[8];
  const float* bo2 = (const float*)d_in[9];
  float* out = (float*)d_out;

  char* ws = (char*)d_ws;
  float*    subj = (float*)ws;                        //  8,192,000 B
  float*    objp = (float*)(ws + 8192000);            //  8,192,000 B
  uint32_t* L    = (uint32_t*)(ws + 16384000);        //        128 B
  uint32_t* cnt  = (uint32_t*)(ws + 16384128);        //        128 B
  uint32_t* cnt2 = (uint32_t*)(ws + 16384256);        //        128 B
  uint32_t* ghist= (uint32_t*)(ws + 16384384);        //    524,288 B
  uint32_t* T    = (uint32_t*)(ws + 16908672);        //        128 B
  uint32_t* flag = (uint32_t*)(ws + 16908800);        //        128 B
  uint2*    cand = (uint2*)   (ws + 16908928);        //  3,932,160 B

  hipMemsetAsync(cnt, 0, 128 + 128 + 524288, stream);

  mlp_kernel<<<ROWS/RB, TPB, 0, stream>>>(x, Ws1, bs1, Ws2, bs2,
                                          Wo1, bo1, Wo2, bo2, subj, objp);
  sample_thresh<<<NB, 1024, 0, stream>>>(subj, objp, L);
  score_pass1<<<NB*64, 256, 0, stream>>>(subj, objp, L, cnt, cand, ghist);
  pick_thresh<<<NB, 256, 0, stream>>>(ghist, cnt, T, flag);
  score_repair<<<NB*64, 256, 0, stream>>>(subj, objp, T, flag, cnt2, cand);
  final_select<<<NB, 1024, 0, stream>>>(cnt, cnt2, flag, cand, out);
}

// Round 12
// 617.647 us; speedup vs baseline: 1.0708x; 1.0708x over previous
//
#include <hip/hip_runtime.h>
#include <cstdint>

#define NB 32
#define NN 1000
#define NC 1601
#define HID 64
#define ROWS (NB*NN)       // 32000
#define CAPB 15360         // candidate cap per batch
#define SROWS 15           // sample rows for threshold floor
#define NBIN 4096          // 12-bit key-prefix histogram
#define KCH 32             // mlp k-chunk
#define RB 64              // mlp rows per block
#define TPB 256            // mlp threads per block
#define XSTR 68            // 64 rows + 4 pad (16B-aligned b128 reads)
#define WSTR 132           // W chunk row stride: 128 cols + 4 pad
#define SSTR 132           // score tile row stride: 128 + 4 pad

__device__ __forceinline__ uint32_t f2key(float f){
  uint32_t u = __float_as_uint(f);
  return (u & 0x80000000u) ? ~u : (u | 0x80000000u);   // monotone float->uint
}
__device__ __forceinline__ float key2f(uint32_t k){
  uint32_t u = (k & 0x80000000u) ? (k & 0x7fffffffu) : ~k;
  return __uint_as_float(u);
}

// ---------------------------------------------------------------------------
// Kernel A: fused 2-layer MLP, tiled GEMM.
// R11: R9 structure (256 thr, 4x(4S+4O) tile, W1-in-LDS dbuf) with a
// batch-load inner body: per 4 k-steps, all 12 ds_read_b128 issue as one
// block, then 4x32 FMAs in k-ascending order. R10's rotated pipeline
// raised VALU busy-time +42% (rotation movs + selects) and regressed
// 254->289us; this version adds ZERO instructions vs R9 while batching
// loads 12-deep for latency cover (kernel is mixed latency-bound:
// VALU 46-58%, LDS ~60-75%, 2 waves/SIMD). Value order per output
// element unchanged -> bit-identical results.
// ---------------------------------------------------------------------------
__global__ __launch_bounds__(TPB, 2) void mlp_kernel(
    const float* __restrict__ x,
    const float* __restrict__ Ws1, const float* __restrict__ bs1,
    const float* __restrict__ Ws2, const float* __restrict__ bs2,
    const float* __restrict__ Wo1, const float* __restrict__ bo1,
    const float* __restrict__ Wo2, const float* __restrict__ bo2,
    float* __restrict__ subj, float* __restrict__ obj)
{
  __shared__ float smem[2*KCH*XSTR + 2*KCH*WSTR];  // 51200 B; reused as hT
  __shared__ float xtail[RB];
  const int tid = threadIdx.x;
  const int tx  = tid & 15;            // col group: subj tx*4..+3, obj tx*4..+3
  const int ty  = tid >> 4;            // row group: rows ty*4..+3 (0..15)
  const int row0 = blockIdx.x * RB;

  float* xbuf = smem;                  // 2 * 32*68
  float* wbuf = smem + 2*KCH*XSTR;     // 2 * 32*132

  float accS[4][4], accO[4][4];
  #pragma unroll
  for (int r=0;r<4;r++)
    #pragma unroll
    for (int c=0;c<4;c++){ accS[r][c]=0.f; accO[r][c]=0.f; }

  // prologue: chunk 0 into regs (x: 2048 floats, W: 1024 float4)
  float  xstg[8];
  float4 wstg[4];
  #pragma unroll
  for (int it=0; it<8; it++){
    int u = tid + it*TPB;
    xstg[it] = x[(size_t)(row0 + (u>>5))*NC + (u&31)];
  }
  #pragma unroll
  for (int it=0; it<4; it++){
    int u = tid + it*TPB;
    int k = u>>5, c4 = u&31;
    const float* src = (c4 < 16) ? (Ws1 + (size_t)k*HID + c4*4)
                                 : (Wo1 + (size_t)k*HID + (c4-16)*4);
    wstg[it] = *(const float4*)src;
  }

  const int NCHUNK = 50;               // 50*32 = 1600, tail k=1600 after
  for (int c = 0; c < NCHUNK; c++){
    float* xT = xbuf + (c & 1)*(KCH*XSTR);
    float* wC = wbuf + (c & 1)*(KCH*WSTR);
    #pragma unroll
    for (int it=0; it<8; it++){
      int u = tid + it*TPB;
      xT[(u&31)*XSTR + (u>>5)] = xstg[it];
    }
    #pragma unroll
    for (int it=0; it<4; it++){
      int u = tid + it*TPB;
      *(float4*)&wC[(u>>5)*WSTR + (u&31)*4] = wstg[it];
    }
    __syncthreads();                   // buffer c ready; buffer c^1 free
    if (c+1 < NCHUNK){
      const int k0n = (c+1)*KCH;
      #pragma unroll
      for (int it=0; it<8; it++){      // global latency hidden by compute(c)
        int u = tid + it*TPB;
        xstg[it] = x[(size_t)(row0 + (u>>5))*NC + k0n + (u&31)];
      }
      #pragma unroll
      for (int it=0; it<4; it++){
        int u = tid + it*TPB;
        int k = u>>5, c4 = u&31;
        const float* src = (c4 < 16) ? (Ws1 + (size_t)(k0n+k)*HID + c4*4)
                                     : (Wo1 + (size_t)(k0n+k)*HID + (c4-16)*4);
        wstg[it] = *(const float4*)src;
      }
    }
    // ---- batch-load inner body: 12 ds_read_b128 then 4x32 FMA ----
    #pragma unroll 2
    for (int k=0; k<KCH; k+=4){
      float4 A0 = *(const float4*)&xT[(k+0)*XSTR + ty*4];
      float4 A1 = *(const float4*)&xT[(k+1)*XSTR + ty*4];
      float4 A2 = *(const float4*)&xT[(k+2)*XSTR + ty*4];
      float4 A3 = *(const float4*)&xT[(k+3)*XSTR + ty*4];
      float4 S0 = *(const float4*)&wC[(k+0)*WSTR + tx*4];
      float4 S1 = *(const float4*)&wC[(k+1)*WSTR + tx*4];
      float4 S2 = *(const float4*)&wC[(k+2)*WSTR + tx*4];
      float4 S3 = *(const float4*)&wC[(k+3)*WSTR + tx*4];
      float4 O0 = *(const float4*)&wC[(k+0)*WSTR + 64 + tx*4];
      float4 O1 = *(const float4*)&wC[(k+1)*WSTR + 64 + tx*4];
      float4 O2 = *(const float4*)&wC[(k+2)*WSTR + 64 + tx*4];
      float4 O3 = *(const float4*)&wC[(k+3)*WSTR + 64 + tx*4];
      #pragma unroll
      for (int kk=0; kk<4; kk++){
        float4 A = kk==0?A0 : kk==1?A1 : kk==2?A2 : A3;
        float4 S = kk==0?S0 : kk==1?S1 : kk==2?S2 : S3;
        float4 O = kk==0?O0 : kk==1?O1 : kk==2?O2 : O3;
        float av[4] = {A.x,A.y,A.z,A.w};
        float bs_[4] = {S.x,S.y,S.z,S.w};
        float bo_[4] = {O.x,O.y,O.z,O.w};
        #pragma unroll
        for (int r=0;r<4;r++)
          #pragma unroll
          for (int c2=0;c2<4;c2++){
            accS[r][c2] = fmaf(av[r], bs_[c2], accS[r][c2]);
            accO[r][c2] = fmaf(av[r], bo_[c2], accO[r][c2]);
          }
      }
    }
  }

  // tail k = 1600 (W via global: 2 loads total, negligible)
  if (tid < RB) xtail[tid] = x[(size_t)(row0 + tid)*NC + 1600];
  __syncthreads();
  {
    float4 a  = *(const float4*)&xtail[ty*4];
    float4 bS = *(const float4*)(Ws1 + (size_t)1600*HID + tx*4);
    float4 bO = *(const float4*)(Wo1 + (size_t)1600*HID + tx*4);
    float av[4] = {a.x,a.y,a.z,a.w};
    float bs_[4] = {bS.x,bS.y,bS.z,bS.w};
    float bo_[4] = {bO.x,bO.y,bO.z,bO.w};
    #pragma unroll
    for (int r=0;r<4;r++)
      #pragma unroll
      for (int c2=0;c2<4;c2++){
        accS[r][c2] = fmaf(av[r], bs_[c2], accS[r][c2]);
        accO[r][c2] = fmaf(av[r], bo_[c2], accO[r][c2]);
      }
  }

  // ---- layer 2: h (bias+ReLU) -> LDS transposed, both heads at once ----
  float* hTS = smem;                   // 64*68
  float* hTO = smem + 64*XSTR;         // 64*68  (34816B total, fits 51456)
  __syncthreads();                     // all xT/wC reads done
  #pragma unroll
  for (int jj=0; jj<4; jj++){
    float bS = bs1[tx*4 + jj];
    float bO = bo1[tx*4 + jj];
    float4 hv;
    hv.x = fmaxf(accS[0][jj]+bS, 0.f); hv.y = fmaxf(accS[1][jj]+bS, 0.f);
    hv.z = fmaxf(accS[2][jj]+bS, 0.f); hv.w = fmaxf(accS[3][jj]+bS, 0.f);
    *(float4*)&hTS[(tx*4+jj)*XSTR + ty*4] = hv;
    hv.x = fmaxf(accO[0][jj]+bO, 0.f); hv.y = fmaxf(accO[1][jj]+bO, 0.f);
    hv.z = fmaxf(accO[2][jj]+bO, 0.f); hv.w = fmaxf(accO[3][jj]+bO, 0.f);
    *(float4*)&hTO[(tx*4+jj)*XSTR + ty*4] = hv;
  }
  __syncthreads();

  float accYS[4][4], accYO[4][4];
  #pragma unroll
  for (int c2=0;c2<4;c2++){
    float bvS = bs2[tx*4 + c2];
    float bvO = bo2[tx*4 + c2];
    #pragma unroll
    for (int r=0;r<4;r++){ accYS[r][c2] = bvS; accYO[r][c2] = bvO; }
  }
  #pragma unroll 4
  for (int d=0; d<64; d++){
    float4 aS = *(const float4*)&hTS[d*XSTR + ty*4];
    float4 aO = *(const float4*)&hTO[d*XSTR + ty*4];
    float4 wS = *(const float4*)(Ws2 + (size_t)d*HID + tx*4);
    float4 wO = *(const float4*)(Wo2 + (size_t)d*HID + tx*4);
    float aSv[4] = {aS.x,aS.y,aS.z,aS.w};
    float aOv[4] = {aO.x,aO.y,aO.z,aO.w};
    float wSv[4] = {wS.x,wS.y,wS.z,wS.w};
    float wOv[4] = {wO.x,wO.y,wO.z,wO.w};
    #pragma unroll
    for (int r=0;r<4;r++)
      #pragma unroll
      for (int c2=0;c2<4;c2++){
        accYS[r][c2] = fmaf(aSv[r], wSv[c2], accYS[r][c2]);
        accYO[r][c2] = fmaf(aOv[r], wOv[c2], accYO[r][c2]);
      }
  }
  #pragma unroll
  for (int r=0;r<4;r++){
    *(float4*)&subj[(size_t)(row0 + ty*4 + r)*HID + tx*4] =
      make_float4(accYS[r][0], accYS[r][1], accYS[r][2], accYS[r][3]);
    *(float4*)&obj[(size_t)(row0 + ty*4 + r)*HID + tx*4] =
      make_float4(accYO[r][0], accYO[r][1], accYO[r][2], accYO[r][3]);
  }
}

// ---------------------------------------------------------------------------
// Kernel B0: per-batch sampled FLOOR. Subset 64th <= full 64th.
// R11: also zeroes ghist/cnt/cnt2 for its batch (replaces the memset
// launch; stream order guarantees completion before score_pass1).
// ---------------------------------------------------------------------------
__global__ __launch_bounds__(1024, 4) void sample_thresh(
    const float* __restrict__ subj, const float* __restrict__ obj,
    uint32_t* __restrict__ L, uint32_t* __restrict__ cnt,
    uint32_t* __restrict__ cnt2, uint32_t* __restrict__ ghist)
{
  __shared__ float sRows[SROWS*HID];
  __shared__ uint32_t keys[SROWS*NN];
  __shared__ uint32_t hist[256];
  __shared__ uint32_t sb[2];
  const int b = blockIdx.x, tid = threadIdx.x;

  // zero per-batch accumulators (was hipMemsetAsync)
  uint32_t* gh = ghist + (size_t)b*NBIN;
  for (int i = tid; i < NBIN; i += 1024) gh[i] = 0u;
  if (tid == 0){ cnt[b] = 0u; cnt2[b] = 0u; }

  const float4* sp = (const float4*)(subj + (size_t)b*NN*HID);
  if (tid < SROWS*16) ((float4*)sRows)[tid] = sp[tid];
  __syncthreads();

  for (int j = tid; j < NN; j += 1024){
    const float4* op4 = (const float4*)(obj + ((size_t)b*NN + j)*HID);
    float4 o[16];
    #pragma unroll
    for (int q=0;q<16;q++) o[q] = op4[q];
    #pragma unroll 1
    for (int i=0;i<SROWS;i++){
      const float4* s4 = (const float4*)(sRows + i*HID);
      float acc = 0.f;
      #pragma unroll
      for (int q=0;q<16;q++){
        float4 s = s4[q];
        acc = fmaf(s.x, o[q].x, acc); acc = fmaf(s.y, o[q].y, acc);
        acc = fmaf(s.z, o[q].z, acc); acc = fmaf(s.w, o[q].w, acc);
      }
      keys[i*NN + j] = f2key(acc);
    }
  }
  __syncthreads();

  uint32_t prefix = 0; int remaining = 64;
  for (int round = 0; round < 2; round++){
    const int shift = 24 - round*8;
    if (tid < 256) hist[tid] = 0;
    __syncthreads();
    for (int idx = tid; idx < SROWS*NN; idx += 1024){
      uint32_t k = keys[idx];
      bool match = (round == 0) || ((k >> 24) == (prefix >> 24));
      if (match) atomicAdd(&hist[(k >> shift) & 255u], 1u);
    }
    __syncthreads();
    if (tid == 0){
      uint32_t cum = 0; int bin = 255;
      for (;; bin--){ cum += hist[bin]; if (cum >= (uint32_t)remaining || bin == 0) break; }
      sb[0] = (uint32_t)bin;
      sb[1] = (uint32_t)(remaining - (int)(cum - hist[bin]));
    }
    __syncthreads();
    prefix |= sb[0] << shift;
    remaining = (int)sb[1];
    __syncthreads();
  }
  if (tid == 0) L[b] = prefix;
}

// ---------------------------------------------------------------------------
// Shared tile-compute for B1/B3: 128x128 tile, k staged in 2 chunks of 32,
// both tiles k-major stride 132 -> b128 fragment reads (broadcast / 4-way).
// FMA chains k-ascending: bitwise-identical across B1 and B3.
// ---------------------------------------------------------------------------
__device__ __forceinline__ void score_tile_acc(
    const float* __restrict__ subj, const float* __restrict__ obj,
    int b, int ti, int tj, int tid,
    float* __restrict__ sT, float* __restrict__ oT, float (&acc)[8][8])
{
  const int tx = tid & 15, ty = tid >> 4;
  #pragma unroll
  for (int a=0;a<8;a++)
    #pragma unroll
    for (int c=0;c<8;c++) acc[a][c] = 0.f;

  #pragma unroll 1
  for (int half = 0; half < 2; half++){
    __syncthreads();                   // previous chunk's reads done
    {
      const float4* gp = (const float4*)subj;
      #pragma unroll
      for (int it=0; it<4; it++){
        int u = tid + it*256;
        int r = u >> 3, q = (u & 7) + half*8;
        int gr = b*NN + ti + r; gr = gr < ROWS ? gr : (ROWS-1);
        float4 v = gp[(size_t)gr*16 + q];
        int kk = (u & 7)*4;
        sT[(kk+0)*SSTR + r] = v.x;
        sT[(kk+1)*SSTR + r] = v.y;
        sT[(kk+2)*SSTR + r] = v.z;
        sT[(kk+3)*SSTR + r] = v.w;
      }
      const float4* gp2 = (const float4*)obj;
      #pragma unroll
      for (int it=0; it<4; it++){
        int u = tid + it*256;
        int r = u >> 3, q = (u & 7) + half*8;
        int gr = b*NN + tj + r; gr = gr < ROWS ? gr : (ROWS-1);
        float4 v = gp2[(size_t)gr*16 + q];
        int kk = (u & 7)*4;
        oT[(kk+0)*SSTR + r] = v.x;
        oT[(kk+1)*SSTR + r] = v.y;
        oT[(kk+2)*SSTR + r] = v.z;
        oT[(kk+3)*SSTR + r] = v.w;
      }
    }
    __syncthreads();
    #pragma unroll 2
    for (int k=0; k<32; k++){
      float4 s0 = *(const float4*)&sT[k*SSTR + ty*8];
      float4 s1 = *(const float4*)&sT[k*SSTR + ty*8 + 4];
      float4 o0 = *(const float4*)&oT[k*SSTR + tx*8];
      float4 o1 = *(const float4*)&oT[k*SSTR + tx*8 + 4];
      float s[8] = {s0.x,s0.y,s0.z,s0.w,s1.x,s1.y,s1.z,s1.w};
      float o[8] = {o0.x,o0.y,o0.z,o0.w,o1.x,o1.y,o1.z,o1.w};
      #pragma unroll
      for (int a=0;a<8;a++)
        #pragma unroll
        for (int c=0;c<8;c++)
          acc[a][c] = fmaf(s[a], o[c], acc[a][c]);
    }
  }
}

// ---------------------------------------------------------------------------
// Kernel B1: score tiles; 12-bit histogram of keys >= L[b] + candidate
// append via two-phase reservation (1 global atomic per block).
// ---------------------------------------------------------------------------
__global__ __launch_bounds__(256, 3) void score_pass1(
    const float* __restrict__ subj, const float* __restrict__ obj,
    const uint32_t* __restrict__ L, uint32_t* __restrict__ cnt,
    uint2* __restrict__ cand, uint32_t* __restrict__ ghist)
{
  __shared__ float sT[32*SSTR];       // 16896 B
  __shared__ float oT[32*SSTR];       // 16896 B
  __shared__ uint32_t hist[NBIN];     // 16384 B
  __shared__ uint32_t lcnt, gbase;
  const int blk = blockIdx.x;
  const int b   = blk >> 6;
  const int t   = blk & 63;
  const int ti  = (t >> 3) << 7;
  const int tj  = (t & 7)  << 7;
  const int tid = threadIdx.x;
  const int tx = tid & 15, ty = tid >> 4;

  for (int i = tid; i < NBIN; i += 256) hist[i] = 0;
  if (tid == 0) lcnt = 0;

  float acc[8][8];
  score_tile_acc(subj, obj, b, ti, tj, tid, sT, oT, acc);

  const uint32_t Lb = L[b];
  int myCnt = 0;
  #pragma unroll
  for (int a=0;a<8;a++){
    int gi = ti + ty*8 + a;
    #pragma unroll
    for (int c=0;c<8;c++){
      int gj = tj + tx*8 + c;
      if (gi < NN && gj < NN){
        uint32_t key = f2key(acc[a][c]);
        if (key >= Lb){ myCnt++; atomicAdd(&hist[key >> 20], 1u); }
      }
    }
  }
  uint32_t lbase = atomicAdd(&lcnt, (uint32_t)myCnt);
  __syncthreads();
  if (tid == 0) gbase = atomicAdd(&cnt[b], lcnt);
  __syncthreads();
  uint32_t pos = gbase + lbase;
  #pragma unroll
  for (int a=0;a<8;a++){
    int gi = ti + ty*8 + a;
    #pragma unroll
    for (int c=0;c<8;c++){
      int gj = tj + tx*8 + c;
      if (gi < NN && gj < NN){
        uint32_t key = f2key(acc[a][c]);
        if (key >= Lb){
          if (pos < CAPB) cand[(size_t)b*CAPB + pos] = make_uint2(key, (uint32_t)(gi*NN + gj));
          pos++;
        }
      }
    }
  }
  __syncthreads();
  for (int i = tid; i < NBIN; i += 256){
    uint32_t v = hist[i];
    if (v) atomicAdd(&ghist[(size_t)b*NBIN + i], v);
  }
}

// ---------------------------------------------------------------------------
// Kernel B2: exact 12-bit bucket floor T[b] of the 64th-largest key;
// flag[b] = candidate overflow.
// ---------------------------------------------------------------------------
__global__ __launch_bounds__(256, 1) void pick_thresh(
    const uint32_t* __restrict__ ghist, const uint32_t* __restrict__ cnt,
    uint32_t* __restrict__ T, uint32_t* __restrict__ flag)
{
  __shared__ uint32_t S[256];
  const int b = blockIdx.x, tid = threadIdx.x;
  const uint32_t* h = ghist + (size_t)b*NBIN;
  uint32_t loc[16];
  uint32_t s = 0;
  #pragma unroll
  for (int i=0;i<16;i++){ loc[i] = h[tid*16 + i]; s += loc[i]; }
  S[tid] = s;
  __syncthreads();
  for (int off = 1; off < 256; off <<= 1){
    uint32_t v = (tid + off < 256) ? S[tid + off] : 0u;
    __syncthreads();
    S[tid] += v;
    __syncthreads();
  }
  uint32_t above = (tid < 255) ? S[tid + 1] : 0u;
  if (above < 64u && S[tid] >= 64u){
    uint32_t suf = above; int best = 0;
    for (int i=15;i>=0;i--){ suf += loc[i]; if (suf >= 64u){ best = i; break; } }
    T[b] = (uint32_t)(tid*16 + best) << 20;
  }
  if (tid == 0) flag[b] = (cnt[b] > (uint32_t)CAPB) ? 1u : 0u;
}

// ---------------------------------------------------------------------------
// Kernel B3: repair pass for overflowed batches (early-exit common case).
// Identical dot chains to B1.
// ---------------------------------------------------------------------------
__global__ __launch_bounds__(256, 3) void score_repair(
    const float* __restrict__ subj, const float* __restrict__ obj,
    const uint32_t* __restrict__ T, const uint32_t* __restrict__ flag,
    uint32_t* __restrict__ cnt2, uint2* __restrict__ cand)
{
  const int blk = blockIdx.x;
  const int b   = blk >> 6;
  if (flag[b] == 0u) return;

  __shared__ float sT[32*SSTR];
  __shared__ float oT[32*SSTR];
  __shared__ uint32_t lcnt, gbase;
  const int t   = blk & 63;
  const int ti  = (t >> 3) << 7;
  const int tj  = (t & 7)  << 7;
  const int tid = threadIdx.x;
  const int tx = tid & 15, ty = tid >> 4;

  if (tid == 0) lcnt = 0;

  float acc[8][8];
  score_tile_acc(subj, obj, b, ti, tj, tid, sT, oT, acc);

  const uint32_t Tb = T[b];
  int myCnt = 0;
  #pragma unroll
  for (int a=0;a<8;a++){
    int gi = ti + ty*8 + a;
    #pragma unroll
    for (int c=0;c<8;c++){
      int gj = tj + tx*8 + c;
      if (gi < NN && gj < NN && f2key(acc[a][c]) >= Tb) myCnt++;
    }
  }
  uint32_t lbase = atomicAdd(&lcnt, (uint32_t)myCnt);
  __syncthreads();
  if (tid == 0) gbase = atomicAdd(&cnt2[b], lcnt);
  __syncthreads();
  uint32_t pos = gbase + lbase;
  #pragma unroll
  for (int a=0;a<8;a++){
    int gi = ti + ty*8 + a;
    #pragma unroll
    for (int c=0;c<8;c++){
      int gj = tj + tx*8 + c;
      if (gi < NN && gj < NN){
        uint32_t key = f2key(acc[a][c]);
        if (key >= Tb){
          if (pos < CAPB) cand[(size_t)b*CAPB + pos] = make_uint2(key, (uint32_t)(gi*NN + gj));
          pos++;
        }
      }
    }
  }
}

// ---------------------------------------------------------------------------
// Kernel C: exact top-64 per batch. Radix-select 64th key, rank by
// (value desc, index asc) = jax.lax.top_k tie semantics.
// ---------------------------------------------------------------------------
__global__ __launch_bounds__(1024, 4) void final_select(
    const uint32_t* __restrict__ cnt, const uint32_t* __restrict__ cnt2,
    const uint32_t* __restrict__ flag, const uint2* __restrict__ cand,
    float* __restrict__ out)
{
  __shared__ uint32_t keys[CAPB];
  __shared__ uint32_t hist[256];
  __shared__ uint32_t sb[2];
  __shared__ uint2 win[192];
  __shared__ uint32_t wn;
  const int b = blockIdx.x, tid = threadIdx.x;
  uint32_t n0 = flag[b] ? cnt2[b] : cnt[b];
  const int n = (n0 < (uint32_t)CAPB) ? (int)n0 : CAPB;

  for (int i = tid; i < n; i += 1024) keys[i] = cand[(size_t)b*CAPB + i].x;
  if (tid == 0) wn = 0;
  __syncthreads();

  uint32_t prefix = 0; int remaining = 64;
  for (int round = 0; round < 4; round++){
    const int shift = 24 - round*8;
    if (tid < 256) hist[tid] = 0;
    __syncthreads();
    for (int i = tid; i < n; i += 1024){
      uint32_t k = keys[i];
      bool match = (round == 0) || ((k >> (shift+8)) == (prefix >> (shift+8)));
      if (match) atomicAdd(&hist[(k >> shift) & 255u], 1u);
    }
    __syncthreads();
    if (tid == 0){
      uint32_t cum = 0; int bin = 255;
      for (;; bin--){ cum += hist[bin]; if (cum >= (uint32_t)remaining || bin == 0) break; }
      sb[0] = (uint32_t)bin;
      sb[1] = (uint32_t)(remaining - (int)(cum - hist[bin]));
    }
    __syncthreads();
    prefix |= sb[0] << shift;
    remaining = (int)sb[1];
    __syncthreads();
  }
  const uint32_t Tk = prefix;

  for (int i = tid; i < n; i += 1024){
    if (keys[i] >= Tk){
      uint32_t p = atomicAdd(&wn, 1u);
      if (p < 192u) win[p] = make_uint2(keys[i], cand[(size_t)b*CAPB + i].y);
    }
  }
  __syncthreads();
  const int m = (wn < 192u) ? (int)wn : 192;

  if (tid < m){
    const uint64_t me = ((uint64_t)win[tid].x << 32) | (uint64_t)(uint32_t)(~win[tid].y);
    int rank = 0;
    for (int s = 0; s < m; s++){
      uint64_t oth = ((uint64_t)win[s].x << 32) | (uint64_t)(uint32_t)(~win[s].y);
      rank += (oth > me) ? 1 : 0;
    }
    if (rank < 64){
      const uint32_t f = win[tid].y;
      const float d  = key2f(win[tid].x);
      const float sc = 1.0f / (1.0f + expf(-d));
      out[((size_t)b*64 + rank)*2 + 0] = (float)(f / NN);
      out[((size_t)b*64 + rank)*2 + 1] = (float)(f % NN);
      out[(size_t)NB*64*2 + (size_t)b*64 + rank] = sc;
    }
  }
}

// ---------------------------------------------------------------------------
extern "C" void kernel_launch(void* const* d_in, const int* in_sizes, int n_in,
                              void* d_out, int out_size, void* d_ws, size_t ws_size,
                              hipStream_t stream) {
  const float* x   = (const float*)d_in[0];
  const float* Ws1 = (const float*)d_in[2];
  const float* bs1 = (const float*)d_in[3];
  const float* Ws2 = (const float*)d_in[4];
  const float* bs2 = (const float*)d_in[5];
  const float* Wo1 = (const float*)d_in[6];
  const float* bo1 = (const float*)d_in[7];
  const float* Wo2 = (const float*)d_in[8];
  const float* bo2 = (const float*)d_in[9];
  float* out = (float*)d_out;

  char* ws = (char*)d_ws;
  float*    subj = (float*)ws;                        //  8,192,000 B
  float*    objp = (float*)(ws + 8192000);            //  8,192,000 B
  uint32_t* L    = (uint32_t*)(ws + 16384000);        //        128 B
  uint32_t* cnt  = (uint32_t*)(ws + 16384128);        //        128 B
  uint32_t* cnt2 = (uint32_t*)(ws + 16384256);        //        128 B
  uint32_t* ghist= (uint32_t*)(ws + 16384384);        //    524,288 B
  uint32_t* T    = (uint32_t*)(ws + 16908672);        //        128 B
  uint32_t* flag = (uint32_t*)(ws + 16908800);        //        128 B
  uint2*    cand = (uint2*)   (ws + 16908928);        //  3,932,160 B

  mlp_kernel<<<ROWS/RB, TPB, 0, stream>>>(x, Ws1, bs1, Ws2, bs2,
                                          Wo1, bo1, Wo2, bo2, subj, objp);
  sample_thresh<<<NB, 1024, 0, stream>>>(subj, objp, L, cnt, cnt2, ghist);
  score_pass1<<<NB*64, 256, 0, stream>>>(subj, objp, L, cnt, cand, ghist);
  pick_thresh<<<NB, 256, 0, stream>>>(ghist, cnt, T, flag);
  score_repair<<<NB*64, 256, 0, stream>>>(subj, objp, T, flag, cnt2, cand);
  final_select<<<NB, 1024, 0, stream>>>(cnt, cnt2, flag, cand, out);
}